// Round 12
// baseline (1757.214 us; speedup 1.0000x reference)
//
#include <hip/hip_runtime.h>
#include <cstdint>

#define Eexp 8
#define Bb   16384
#define Dd   512
#define Hh   512
#define Zz   64

typedef _Float16 f16x8 __attribute__((ext_vector_type(8)));
typedef float    f32x4 __attribute__((ext_vector_type(4)));

// fm16 layout: per (T=row/16, kb=k/32) a 1024-f16 block [hi 512 | lo 512];
// lane l elem j = M[T*16 + (l&15)][kb*32 + (l>>4)*8 + j]
#define OFF_ENCIN  0
#define OFF_HID0   524288
#define OFF_HID1   1048576
#define OFF_HEADS  1572864   /* mu tiles T0..3, lv tiles T4..7 */
#define OFF_DECIN  1703936
#define OFF_DHID0  1769472
#define OFF_DHID1  2293760
#define OFF_DECOUT 2818048
#define PEREXP     3342336
#define WT_TOTAL   (8 * (size_t)PEREXP)

#define GLL16(g, l) __builtin_amdgcn_global_load_lds( \
    (const __attribute__((address_space(1))) void*)(g), \
    (__attribute__((address_space(3))) void*)(l), 16, 0, 0)

// ---------------------------------------------------------------------------
// fp32 src -> fm16 split-f16. TR: src[K,N] (weights). !TR: src[M,K] (x).
// ---------------------------------------------------------------------------
template<bool TR>
__global__ __launch_bounds__(256)
void fmsplit(const float* __restrict__ src, _Float16* __restrict__ dst,
             int KTOT, int inner, long sStride, long dStride)
{
    __shared__ float t[64][65];
    const int e  = blockIdx.z;
    const int o0 = blockIdx.x * 64;
    const int k0 = blockIdx.y * 64;
    const float* S = src + (size_t)e * sStride;
    _Float16*    D = dst + (size_t)e * dStride;
    const int tid = threadIdx.x;
    const int rr = tid >> 4, c4 = (tid & 15) * 4;
    #pragma unroll
    for (int p = 0; p < 4; ++p) {
        const int r = rr + p * 16;
        const float4 v = *reinterpret_cast<const float4*>(
            S + (size_t)(TR ? (k0 + r) : (o0 + r)) * inner + (TR ? o0 : k0) + c4);
        t[r][c4 + 0] = v.x; t[r][c4 + 1] = v.y;
        t[r][c4 + 2] = v.z; t[r][c4 + 3] = v.w;
    }
    __syncthreads();
    const int lane = tid & 63, wid = tid >> 6;
    const int KB = KTOT >> 5;
    #pragma unroll
    for (int p = 0; p < 2; ++p) {
        const int g  = wid * 2 + p;          // 0..7 = (ot 0..3, kb 0..1)
        const int ot = g >> 1, kb = g & 1;
        const int rI = ot * 16 + (lane & 15);
        const int kI = kb * 32 + (lane >> 4) * 8;
        f16x8 hv, lv;
        #pragma unroll
        for (int j = 0; j < 8; ++j) {
            const float v = TR ? t[kI + j][rI] : t[rI][kI + j];
            const _Float16 h = (_Float16)v;
            hv[j] = h; lv[j] = (_Float16)(v - (float)h);
        }
        const size_t base = ((size_t)((o0 >> 4) + ot) * KB + (k0 >> 5) + kb) * 1024;
        *reinterpret_cast<f16x8*>(D + base + lane * 8)       = hv;
        *reinterpret_cast<f16x8*>(D + base + 512 + lane * 8) = lv;
    }
}

// ---------------------------------------------------------------------------
// MODE0 hidden-layer GEMM (unchanged r11 structure): relu -> fm16 out.
// BM=128,BN=128, 4 waves 2x2, wave 64x64, grid 512, ring-2 counted vmcnt.
// ---------------------------------------------------------------------------
template<int KA>
__global__ __launch_bounds__(256, 2)
void gemm_mid(const _Float16* __restrict__ Afm, const _Float16* __restrict__ Wfm,
              const float* __restrict__ bias0, _Float16* __restrict__ Cfm)
{
    constexpr int KB  = KA / 32;
    constexpr int NT  = KB;
    constexpr int ACH = 16;
    constexpr int NCH = 32;
    constexpr int GPW = 8;
    __shared__ __align__(16) _Float16 lds[2 * NCH * 512];

    const int bid = blockIdx.x;
    const int bx = (bid & 7) * 16 + (bid >> 5);
    const int by = (bid >> 3) & 3;

    const int lane = threadIdx.x & 63, wid = threadIdx.x >> 6;
    const int wr = wid >> 1, wc = wid & 1;
    const int row0 = bx * 128;
    const int col0 = by * 128;

    const _Float16* src[GPW];
    #pragma unroll
    for (int p = 0; p < GPW; ++p) {
        const int q = wid * GPW + p;
        if (q < ACH)
            src[p] = Afm + (size_t)((row0 >> 4) + (q >> 1)) * KB * 1024
                         + (q & 1) * 512 + lane * 8;
        else {
            const int qq = q - ACH;
            src[p] = Wfm + (size_t)((col0 >> 4) + (qq >> 1)) * KB * 1024
                         + (qq & 1) * 512 + lane * 8;
        }
    }

    f32x4 acc[4][4];
    #pragma unroll
    for (int i = 0; i < 4; ++i)
        #pragma unroll
        for (int j = 0; j < 4; ++j) acc[i][j] = {0.f, 0.f, 0.f, 0.f};

#define STAGE(buf)                                                           \
    { _Pragma("unroll")                                                      \
      for (int p = 0; p < GPW; ++p) {                                        \
          GLL16(src[p], lds + (buf) * (NCH * 512) + (wid * GPW + p) * 512);  \
          src[p] += 1024;                                                    \
      } }

    STAGE(0)
    if (NT > 1) STAGE(1)

    for (int t = 0; t < NT; ++t) {
        if (t + 1 < NT) { asm volatile("s_waitcnt vmcnt(%0)" :: "i"(GPW) : "memory"); }
        else            { asm volatile("s_waitcnt vmcnt(0)" ::: "memory"); }
        __builtin_amdgcn_s_barrier();
        asm volatile("" ::: "memory");

        const _Float16* B0 = lds + (t & 1) * (NCH * 512);
        f16x8 ah[4], al[4], wh[4], wl[4];
        #pragma unroll
        for (int mf = 0; mf < 4; ++mf) {
            const int q = (wr * 4 + mf) * 2;
            ah[mf] = *reinterpret_cast<const f16x8*>(B0 + q * 512 + lane * 8);
            al[mf] = *reinterpret_cast<const f16x8*>(B0 + q * 512 + 512 + lane * 8);
        }
        #pragma unroll
        for (int nf = 0; nf < 4; ++nf) {
            const int q = ACH + (wc * 4 + nf) * 2;
            wh[nf] = *reinterpret_cast<const f16x8*>(B0 + q * 512 + lane * 8);
            wl[nf] = *reinterpret_cast<const f16x8*>(B0 + q * 512 + 512 + lane * 8);
        }
        __builtin_amdgcn_s_setprio(1);
        #pragma unroll
        for (int mf = 0; mf < 4; ++mf)
            #pragma unroll
            for (int nf = 0; nf < 4; ++nf) {
                acc[mf][nf] = __builtin_amdgcn_mfma_f32_16x16x32_f16(
                    ah[mf], wh[nf], acc[mf][nf], 0, 0, 0);
                acc[mf][nf] = __builtin_amdgcn_mfma_f32_16x16x32_f16(
                    ah[mf], wl[nf], acc[mf][nf], 0, 0, 0);
                acc[mf][nf] = __builtin_amdgcn_mfma_f32_16x16x32_f16(
                    al[mf], wh[nf], acc[mf][nf], 0, 0, 0);
            }
        __builtin_amdgcn_s_setprio(0);
        asm volatile("" ::: "memory");
        __builtin_amdgcn_s_barrier();
        asm volatile("" ::: "memory");
        if (t + 2 < NT) STAGE(t & 1)
    }
#undef STAGE

    // relu -> packed bounce -> fm16 out (r11 epilogue, 2-way conflicts only)
    uint32_t* sb = reinterpret_cast<uint32_t*>(&lds[0]);
    #pragma unroll
    for (int ph = 0; ph < 2; ++ph) {
        if (wc == ph) {
            #pragma unroll
            for (int nf = 0; nf < 4; ++nf) {
                const int c_l = nf * 16 + (lane & 15);
                const float bv = bias0[col0 + ph * 64 + c_l];
                #pragma unroll
                for (int mf = 0; mf < 4; ++mf)
                    #pragma unroll
                    for (int j = 0; j < 4; ++j) {
                        const int r_l = wr * 64 + mf * 16 + (lane >> 4) * 4 + j;
                        const float v = fmaxf(acc[mf][nf][j] + bv, 0.f);
                        const _Float16 h = (_Float16)v;
                        const _Float16 lo = (_Float16)(v - (float)h);
                        const uint32_t pk =
                            (uint32_t)__builtin_bit_cast(uint16_t, h) |
                            ((uint32_t)__builtin_bit_cast(uint16_t, lo) << 16);
                        sb[r_l * 64 + (((c_l >> 2) ^ (r_l & 15)) << 2) + (c_l & 3)] = pk;
                    }
            }
        }
        __syncthreads();
        {
            #pragma unroll
            for (int i = 0; i < 4; ++i) {
                const int q = wid * 4 + i;
                const int T_l = q >> 1, kb_l = q & 1;
                const int r_l = T_l * 16 + (lane & 15);
                const int cb  = kb_l * 32 + (lane >> 4) * 8;
                uint32_t u[8];
                #pragma unroll
                for (int jb = 0; jb < 2; ++jb) {
                    const int chunk = ((cb >> 2) + jb) ^ (r_l & 15);
                    const uint32_t* pp = &sb[r_l * 64 + chunk * 4];
                    u[jb*4+0] = pp[0]; u[jb*4+1] = pp[1];
                    u[jb*4+2] = pp[2]; u[jb*4+3] = pp[3];
                }
                f16x8 hv, lvv;
                #pragma unroll
                for (int j = 0; j < 8; ++j) {
                    hv[j]  = __builtin_bit_cast(_Float16, (uint16_t)(u[j] & 0xffff));
                    lvv[j] = __builtin_bit_cast(_Float16, (uint16_t)(u[j] >> 16));
                }
                const size_t base =
                    ((size_t)((row0 >> 4) + T_l) * 16 +
                     ((col0 + ph * 64) >> 5) + kb_l) * 1024;
                *reinterpret_cast<f16x8*>(Cfm + base + lane * 8)       = hv;
                *reinterpret_cast<f16x8*>(Cfm + base + 512 + lane * 8) = lvv;
            }
        }
        __syncthreads();
    }
}

// ---------------------------------------------------------------------------
// heads_z: GEMM (A[B,512] x Wheads[128,512]) producing mu|lv, fused with
// reparameterization. BM=64, 4 waves 2x2 (wave 32x64), grid 256.
// Epilogue: mu/lv -> LDS f32 [64][128] -> z=mu+exp(0.5lv)*eps -> zfm split,
// mu_e/lv_e fp32 out.
// ---------------------------------------------------------------------------
__global__ __launch_bounds__(256, 2)
void heads_z(const _Float16* __restrict__ Afm, const _Float16* __restrict__ Wfm,
             const float* __restrict__ mu_b, const float* __restrict__ lv_b,
             const float* __restrict__ eps,
             float* __restrict__ mu_e, float* __restrict__ lv_e,
             _Float16* __restrict__ zfm)
{
    constexpr int KB = 16, NT = 16, ACH = 8, NCH = 24, GPW = 6;
    __shared__ __align__(16) _Float16 lds[2 * NCH * 512];   // 48 KB

    const int bid = blockIdx.x;
    const int bx = (bid & 7) * 32 + (bid >> 3);
    const int lane = threadIdx.x & 63, wid = threadIdx.x >> 6;
    const int wr = wid >> 1, wc = wid & 1;
    const int row0 = bx * 64;

    const _Float16* src[GPW];
    #pragma unroll
    for (int p = 0; p < GPW; ++p) {
        const int q = wid * GPW + p;
        if (q < ACH)
            src[p] = Afm + (size_t)((row0 >> 4) + (q >> 1)) * KB * 1024
                         + (q & 1) * 512 + lane * 8;
        else {
            const int qq = q - ACH;
            src[p] = Wfm + (size_t)(qq >> 1) * KB * 1024 + (qq & 1) * 512 + lane * 8;
        }
    }

    f32x4 acc[2][4];
    #pragma unroll
    for (int i = 0; i < 2; ++i)
        #pragma unroll
        for (int j = 0; j < 4; ++j) acc[i][j] = {0.f, 0.f, 0.f, 0.f};

#define STAGE(buf)                                                           \
    { _Pragma("unroll")                                                      \
      for (int p = 0; p < GPW; ++p) {                                        \
          GLL16(src[p], lds + (buf) * (NCH * 512) + (wid * GPW + p) * 512);  \
          src[p] += 1024;                                                    \
      } }

    STAGE(0)
    STAGE(1)

    for (int t = 0; t < NT; ++t) {
        if (t + 1 < NT) { asm volatile("s_waitcnt vmcnt(%0)" :: "i"(GPW) : "memory"); }
        else            { asm volatile("s_waitcnt vmcnt(0)" ::: "memory"); }
        __builtin_amdgcn_s_barrier();
        asm volatile("" ::: "memory");

        const _Float16* B0 = lds + (t & 1) * (NCH * 512);
        f16x8 ah[2], al[2], wh[4], wl[4];
        #pragma unroll
        for (int mf = 0; mf < 2; ++mf) {
            const int q = (wr * 2 + mf) * 2;
            ah[mf] = *reinterpret_cast<const f16x8*>(B0 + q * 512 + lane * 8);
            al[mf] = *reinterpret_cast<const f16x8*>(B0 + q * 512 + 512 + lane * 8);
        }
        #pragma unroll
        for (int nf = 0; nf < 4; ++nf) {
            const int q = ACH + (wc * 4 + nf) * 2;
            wh[nf] = *reinterpret_cast<const f16x8*>(B0 + q * 512 + lane * 8);
            wl[nf] = *reinterpret_cast<const f16x8*>(B0 + q * 512 + 512 + lane * 8);
        }
        __builtin_amdgcn_s_setprio(1);
        #pragma unroll
        for (int mf = 0; mf < 2; ++mf)
            #pragma unroll
            for (int nf = 0; nf < 4; ++nf) {
                acc[mf][nf] = __builtin_amdgcn_mfma_f32_16x16x32_f16(
                    ah[mf], wh[nf], acc[mf][nf], 0, 0, 0);
                acc[mf][nf] = __builtin_amdgcn_mfma_f32_16x16x32_f16(
                    ah[mf], wl[nf], acc[mf][nf], 0, 0, 0);
                acc[mf][nf] = __builtin_amdgcn_mfma_f32_16x16x32_f16(
                    al[mf], wh[nf], acc[mf][nf], 0, 0, 0);
            }
        __builtin_amdgcn_s_setprio(0);
        asm volatile("" ::: "memory");
        __builtin_amdgcn_s_barrier();
        asm volatile("" ::: "memory");
        if (t + 2 < NT) STAGE(t & 1)
    }
#undef STAGE

    // ---- epilogue: mu|lv -> LDS, z = mu + exp(0.5 lv) * eps ----
    float* mulv = reinterpret_cast<float*>(&lds[0]);    // [64][128]
    #pragma unroll
    for (int nf = 0; nf < 4; ++nf) {
        const int c_h = wc * 64 + nf * 16 + (lane & 15);     // 0..127
        const float bv = (c_h < 64) ? mu_b[c_h] : lv_b[c_h - 64];
        #pragma unroll
        for (int mf = 0; mf < 2; ++mf)
            #pragma unroll
            for (int j = 0; j < 4; ++j) {
                const int r_l = wr * 32 + mf * 16 + (lane >> 4) * 4 + j;
                mulv[r_l * 128 + c_h] = acc[mf][nf][j] + bv;
            }
    }
    __syncthreads();
    const int tid = threadIdx.x;
    #pragma unroll
    for (int k = 0; k < 16; ++k) {
        const int id  = tid + k * 256;       // 0..4095
        const int r_l = id >> 6, c = id & 63;
        const float m = mulv[r_l * 128 + c];
        const float l = mulv[r_l * 128 + 64 + c];
        const size_t go = (size_t)(row0 + r_l) * 64 + c;
        const float ev = eps[go];
        const float z  = m + expf(0.5f * l) * ev;
        mu_e[go] = m; lv_e[go] = l;
        const _Float16 h  = (_Float16)z;
        const _Float16 lo = (_Float16)(z - (float)h);
        const size_t base = ((size_t)((row0 + r_l) >> 4) * 2 + (c >> 5)) * 1024
                            + ((r_l & 15) + ((c >> 3) & 3) * 16) * 8 + (c & 7);
        zfm[base]       = h;
        zfm[base + 512] = lo;
    }
}

// ---------------------------------------------------------------------------
// dec_out_fused: xhat GEMM (full row per block: BM=64, BN=512) + per-row SSE
// + running-min select + conditional winner writes straight to d_out.
// 512 thr = 8 waves, wave 64x64 over col-band wid*64. grid 256. LDS 144 KB.
// ---------------------------------------------------------------------------
__global__ __launch_bounds__(512, 2)
void dec_out_fused(const _Float16* __restrict__ Afm, const _Float16* __restrict__ Wfm,
                   const float* __restrict__ bias,
                   const float* __restrict__ Xin,
                   const float* __restrict__ mu_e, const float* __restrict__ lv_e,
                   float* __restrict__ best,
                   float* __restrict__ out_mu, float* __restrict__ out_lv,
                   float* __restrict__ out_xh, int isFirst)
{
    constexpr int KB = 16, NT = 16, ACH = 8, NCH = 72, GPW = 9;
    __shared__ __align__(16) _Float16 lds[2 * NCH * 512];   // 144 KB

    const int bid = blockIdx.x;
    const int bx = (bid & 7) * 32 + (bid >> 3);
    const int lane = threadIdx.x & 63, wid = threadIdx.x >> 6;
    const int row0 = bx * 64;
    const int colW = wid * 64;

    const _Float16* src[GPW];
    #pragma unroll
    for (int p = 0; p < GPW; ++p) {
        const int q = wid * GPW + p;
        if (q < ACH)
            src[p] = Afm + (size_t)((row0 >> 4) + (q >> 1)) * KB * 1024
                         + (q & 1) * 512 + lane * 8;
        else {
            const int qq = q - ACH;
            src[p] = Wfm + (size_t)(qq >> 1) * KB * 1024 + (qq & 1) * 512 + lane * 8;
        }
    }

    f32x4 acc[4][4];
    #pragma unroll
    for (int i = 0; i < 4; ++i)
        #pragma unroll
        for (int j = 0; j < 4; ++j) acc[i][j] = {0.f, 0.f, 0.f, 0.f};

#define STAGE(buf)                                                           \
    { _Pragma("unroll")                                                      \
      for (int p = 0; p < GPW; ++p) {                                        \
          GLL16(src[p], lds + (buf) * (NCH * 512) + (wid * GPW + p) * 512);  \
          src[p] += 1024;                                                    \
      } }

    STAGE(0)
    STAGE(1)

    for (int t = 0; t < NT; ++t) {
        if (t + 1 < NT) { asm volatile("s_waitcnt vmcnt(%0)" :: "i"(GPW) : "memory"); }
        else            { asm volatile("s_waitcnt vmcnt(0)" ::: "memory"); }
        __builtin_amdgcn_s_barrier();
        asm volatile("" ::: "memory");

        const _Float16* B0 = lds + (t & 1) * (NCH * 512);
        f16x8 ah[4], al[4], wh[4], wl[4];
        #pragma unroll
        for (int mf = 0; mf < 4; ++mf) {
            const int q = mf * 2;
            ah[mf] = *reinterpret_cast<const f16x8*>(B0 + q * 512 + lane * 8);
            al[mf] = *reinterpret_cast<const f16x8*>(B0 + q * 512 + 512 + lane * 8);
        }
        #pragma unroll
        for (int nf = 0; nf < 4; ++nf) {
            const int q = ACH + (wid * 4 + nf) * 2;
            wh[nf] = *reinterpret_cast<const f16x8*>(B0 + q * 512 + lane * 8);
            wl[nf] = *reinterpret_cast<const f16x8*>(B0 + q * 512 + 512 + lane * 8);
        }
        __builtin_amdgcn_s_setprio(1);
        #pragma unroll
        for (int mf = 0; mf < 4; ++mf)
            #pragma unroll
            for (int nf = 0; nf < 4; ++nf) {
                acc[mf][nf] = __builtin_amdgcn_mfma_f32_16x16x32_f16(
                    ah[mf], wh[nf], acc[mf][nf], 0, 0, 0);
                acc[mf][nf] = __builtin_amdgcn_mfma_f32_16x16x32_f16(
                    ah[mf], wl[nf], acc[mf][nf], 0, 0, 0);
                acc[mf][nf] = __builtin_amdgcn_mfma_f32_16x16x32_f16(
                    al[mf], wh[nf], acc[mf][nf], 0, 0, 0);
            }
        __builtin_amdgcn_s_setprio(0);
        asm volatile("" ::: "memory");
        __builtin_amdgcn_s_barrier();
        asm volatile("" ::: "memory");
        if (t + 2 < NT) STAGE(t & 1)
    }
#undef STAGE

    // ---- epilogue: SSE partials, cross-wave reduce, select, winner writes --
    float*    recP = reinterpret_cast<float*>(&lds[0]);      // [8][64]
    int*      winf = reinterpret_cast<int*>(recP + 8 * 64);  // [64]

    float rsum[4][4];
    #pragma unroll
    for (int mf = 0; mf < 4; ++mf)
        #pragma unroll
        for (int j = 0; j < 4; ++j) rsum[mf][j] = 0.f;
    float bv[4];
    #pragma unroll
    for (int nf = 0; nf < 4; ++nf) bv[nf] = bias[colW + nf * 16 + (lane & 15)];
    #pragma unroll
    for (int nf = 0; nf < 4; ++nf) {
        const int col = colW + nf * 16 + (lane & 15);
        #pragma unroll
        for (int mf = 0; mf < 4; ++mf)
            #pragma unroll
            for (int j = 0; j < 4; ++j) {
                const int r_l = mf * 16 + (lane >> 4) * 4 + j;
                const float v = acc[mf][nf][j] + bv[nf];
                const float d = v - Xin[(size_t)(row0 + r_l) * 512 + col];
                rsum[mf][j] += d * d;
            }
    }
    #pragma unroll
    for (int mf = 0; mf < 4; ++mf)
        #pragma unroll
        for (int j = 0; j < 4; ++j) {
            float s = rsum[mf][j];
            s += __shfl_xor(s, 1); s += __shfl_xor(s, 2);
            s += __shfl_xor(s, 4); s += __shfl_xor(s, 8);
            if ((lane & 15) == 0)
                recP[wid * 64 + mf * 16 + (lane >> 4) * 4 + j] = s;
        }
    __syncthreads();
    if (wid == 0) {
        float r = 0.f;
        #pragma unroll
        for (int w = 0; w < 8; ++w) r += recP[w * 64 + lane];
        const int grow = row0 + lane;
        const bool w = isFirst || (r < best[grow]);
        if (w) best[grow] = r;
        winf[lane] = w ? 1 : 0;
    }
    __syncthreads();
    // xhat: each wave writes its 64 cols for winning rows
    #pragma unroll
    for (int mf = 0; mf < 4; ++mf)
        #pragma unroll
        for (int j = 0; j < 4; ++j) {
            const int r_l = mf * 16 + (lane >> 4) * 4 + j;
            if (winf[r_l]) {
                #pragma unroll
                for (int nf = 0; nf < 4; ++nf) {
                    const int col = colW + nf * 16 + (lane & 15);
                    out_xh[(size_t)(row0 + r_l) * 512 + col] = acc[mf][nf][j] + bv[nf];
                }
            }
        }
    // mu/lv gather: wave 0 -> mu, wave 1 -> lv
    if (wid == 0) {
        for (int r = 0; r < 64; ++r)
            if (winf[r]) {
                const size_t o = (size_t)(row0 + r) * 64 + lane;
                out_mu[o] = mu_e[o];
            }
    } else if (wid == 1) {
        for (int r = 0; r < 64; ++r)
            if (winf[r]) {
                const size_t o = (size_t)(row0 + r) * 64 + lane;
                out_lv[o] = lv_e[o];
            }
    }
}

extern "C" void kernel_launch(void* const* d_in, const int* in_sizes, int n_in,
                              void* d_out, int out_size, void* d_ws, size_t ws_size,
                              hipStream_t stream)
{
    const float* x         = (const float*)d_in[0];
    const float* eps       = (const float*)d_in[1];
    const float* enc_in_w  = (const float*)d_in[2];
    const float* enc_in_b  = (const float*)d_in[3];
    const float* enc_hid_w = (const float*)d_in[4];
    const float* enc_hid_b = (const float*)d_in[5];
    const float* mu_w      = (const float*)d_in[6];
    const float* mu_b      = (const float*)d_in[7];
    const float* lv_w      = (const float*)d_in[8];
    const float* lv_b      = (const float*)d_in[9];
    const float* dec_in_w  = (const float*)d_in[10];
    const float* dec_in_b  = (const float*)d_in[11];
    const float* dec_hid_w = (const float*)d_in[12];
    const float* dec_hid_b = (const float*)d_in[13];
    const float* dec_out_w = (const float*)d_in[14];
    const float* dec_out_b = (const float*)d_in[15];

    const size_t FM = (size_t)Bb * 512 * 2;
    const size_t BZ = (size_t)Bb * 64;

    _Float16* wt  = (_Float16*)d_ws;
    _Float16* xfm = wt + WT_TOTAL;
    _Float16* afm = xfm + FM;
    _Float16* bfm = afm + FM;
    _Float16* zfm = bfm + FM;
    float* fbase  = (float*)(zfm + (size_t)Bb * 64 * 2);
    float* mu_e   = fbase;
    float* lv_e   = mu_e + BZ;
    float* best   = lv_e + BZ;

    float* out_mu = (float*)d_out;
    float* out_lv = out_mu + (size_t)Bb * Zz;
    float* out_xh = out_lv + (size_t)Bb * Zz;

    const dim3 blk(256);

    fmsplit<true ><<<dim3(8, 8, 8), blk, 0, stream>>>(enc_in_w,           wt + OFF_ENCIN,  512, 512, 262144, PEREXP);
    fmsplit<true ><<<dim3(8, 8, 8), blk, 0, stream>>>(enc_hid_w,          wt + OFF_HID0,   512, 512, 524288, PEREXP);
    fmsplit<true ><<<dim3(8, 8, 8), blk, 0, stream>>>(enc_hid_w + 262144, wt + OFF_HID1,   512, 512, 524288, PEREXP);
    fmsplit<true ><<<dim3(1, 8, 8), blk, 0, stream>>>(mu_w,               wt + OFF_HEADS,  512,  64,  32768, PEREXP);
    fmsplit<true ><<<dim3(1, 8, 8), blk, 0, stream>>>(lv_w,        wt + OFF_HEADS + 65536, 512,  64,  32768, PEREXP);
    fmsplit<true ><<<dim3(8, 1, 8), blk, 0, stream>>>(dec_in_w,           wt + OFF_DECIN,   64, 512,  32768, PEREXP);
    fmsplit<true ><<<dim3(8, 8, 8), blk, 0, stream>>>(dec_hid_w,          wt + OFF_DHID0,  512, 512, 524288, PEREXP);
    fmsplit<true ><<<dim3(8, 8, 8), blk, 0, stream>>>(dec_hid_w + 262144, wt + OFF_DHID1,  512, 512, 524288, PEREXP);
    fmsplit<true ><<<dim3(8, 8, 8), blk, 0, stream>>>(dec_out_w,          wt + OFF_DECOUT, 512, 512, 262144, PEREXP);
    fmsplit<false><<<dim3(256, 8, 1), blk, 0, stream>>>(x,                xfm,             512, 512, 0, 0);

    const dim3 g512(512), g256(256), blk512(512);

    for (int e = 0; e < Eexp; ++e) {
        const _Float16* we = wt + (size_t)e * PEREXP;
        gemm_mid<512><<<g512, blk, 0, stream>>>(
            xfm, we + OFF_ENCIN, enc_in_b + (size_t)e * Hh, afm);
        gemm_mid<512><<<g512, blk, 0, stream>>>(
            afm, we + OFF_HID0, enc_hid_b + ((size_t)e * 2 + 0) * Hh, bfm);
        gemm_mid<512><<<g512, blk, 0, stream>>>(
            bfm, we + OFF_HID1, enc_hid_b + ((size_t)e * 2 + 1) * Hh, afm);
        heads_z<<<g256, blk, 0, stream>>>(
            afm, we + OFF_HEADS, mu_b + (size_t)e * Zz, lv_b + (size_t)e * Zz,
            eps, mu_e, lv_e, zfm);
        gemm_mid< 64><<<g512, blk, 0, stream>>>(
            zfm, we + OFF_DECIN, dec_in_b + (size_t)e * Hh, bfm);
        gemm_mid<512><<<g512, blk, 0, stream>>>(
            bfm, we + OFF_DHID0, dec_hid_b + ((size_t)e * 2 + 0) * Hh, afm);
        gemm_mid<512><<<g512, blk, 0, stream>>>(
            afm, we + OFF_DHID1, dec_hid_b + ((size_t)e * 2 + 1) * Hh, bfm);
        dec_out_fused<<<g256, blk512, 0, stream>>>(
            bfm, we + OFF_DECOUT, dec_out_b + (size_t)e * Dd,
            x, mu_e, lv_e, best, out_mu, out_lv, out_xh, e == 0 ? 1 : 0);
    }
}

// Round 13
// 1683.277 us; speedup vs baseline: 1.0439x; 1.0439x over previous
//
#include <hip/hip_runtime.h>
#include <cstdint>

#define Eexp 8
#define Bb   16384
#define Dd   512
#define Hh   512
#define Zz   64

typedef _Float16 f16x8 __attribute__((ext_vector_type(8)));
typedef float    f32x4 __attribute__((ext_vector_type(4)));

// fm16 layout: per (T=row/16, kb=k/32) a 1024-f16 block [hi 512 | lo 512];
// lane l elem j = M[T*16 + (l&15)][kb*32 + (l>>4)*8 + j]
#define OFF_ENCIN  0
#define OFF_HID0   524288
#define OFF_HID1   1048576
#define OFF_HEADS  1572864   /* mu tiles T0..3, lv tiles T4..7 */
#define OFF_DECIN  1703936
#define OFF_DHID0  1769472
#define OFF_DHID1  2293760
#define OFF_DECOUT 2818048
#define PEREXP     3342336
#define WT_TOTAL   (8 * (size_t)PEREXP)

#define GLL16(g, l) __builtin_amdgcn_global_load_lds( \
    (const __attribute__((address_space(1))) void*)(g), \
    (__attribute__((address_space(3))) void*)(l), 16, 0, 0)

// ---------------------------------------------------------------------------
// fp32 src -> fm16 split-f16. TR: src[K,N] (weights). !TR: src[M,K] (x).
// ---------------------------------------------------------------------------
template<bool TR>
__global__ __launch_bounds__(256)
void fmsplit(const float* __restrict__ src, _Float16* __restrict__ dst,
             int KTOT, int inner, long sStride, long dStride)
{
    __shared__ float t[64][65];
    const int e  = blockIdx.z;
    const int o0 = blockIdx.x * 64;
    const int k0 = blockIdx.y * 64;
    const float* S = src + (size_t)e * sStride;
    _Float16*    D = dst + (size_t)e * dStride;
    const int tid = threadIdx.x;
    const int rr = tid >> 4, c4 = (tid & 15) * 4;
    #pragma unroll
    for (int p = 0; p < 4; ++p) {
        const int r = rr + p * 16;
        const float4 v = *reinterpret_cast<const float4*>(
            S + (size_t)(TR ? (k0 + r) : (o0 + r)) * inner + (TR ? o0 : k0) + c4);
        t[r][c4 + 0] = v.x; t[r][c4 + 1] = v.y;
        t[r][c4 + 2] = v.z; t[r][c4 + 3] = v.w;
    }
    __syncthreads();
    const int lane = tid & 63, wid = tid >> 6;
    const int KB = KTOT >> 5;
    #pragma unroll
    for (int p = 0; p < 2; ++p) {
        const int g  = wid * 2 + p;          // 0..7 = (ot 0..3, kb 0..1)
        const int ot = g >> 1, kb = g & 1;
        const int rI = ot * 16 + (lane & 15);
        const int kI = kb * 32 + (lane >> 4) * 8;
        f16x8 hv, lv;
        #pragma unroll
        for (int j = 0; j < 8; ++j) {
            const float v = TR ? t[kI + j][rI] : t[rI][kI + j];
            const _Float16 h = (_Float16)v;
            hv[j] = h; lv[j] = (_Float16)(v - (float)h);
        }
        const size_t base = ((size_t)((o0 >> 4) + ot) * KB + (k0 >> 5) + kb) * 1024;
        *reinterpret_cast<f16x8*>(D + base + lane * 8)       = hv;
        *reinterpret_cast<f16x8*>(D + base + 512 + lane * 8) = lv;
    }
}

// ---------------------------------------------------------------------------
// Hidden-layer GEMM (r11-proven): relu -> fm16 out.
// BM=128,BN=128, 4 waves 2x2, wave 64x64, grid 512, ring-2 counted vmcnt.
// ---------------------------------------------------------------------------
template<int KA>
__global__ __launch_bounds__(256, 2)
void gemm_mid(const _Float16* __restrict__ Afm, const _Float16* __restrict__ Wfm,
              const float* __restrict__ bias0, _Float16* __restrict__ Cfm)
{
    constexpr int KB  = KA / 32;
    constexpr int NT  = KB;
    constexpr int ACH = 16;
    constexpr int NCH = 32;
    constexpr int GPW = 8;
    __shared__ __align__(16) _Float16 lds[2 * NCH * 512];

    const int bid = blockIdx.x;
    const int bx = (bid & 7) * 16 + (bid >> 5);
    const int by = (bid >> 3) & 3;

    const int lane = threadIdx.x & 63, wid = threadIdx.x >> 6;
    const int wr = wid >> 1, wc = wid & 1;
    const int row0 = bx * 128;
    const int col0 = by * 128;

    const _Float16* src[GPW];
    #pragma unroll
    for (int p = 0; p < GPW; ++p) {
        const int q = wid * GPW + p;
        if (q < ACH)
            src[p] = Afm + (size_t)((row0 >> 4) + (q >> 1)) * KB * 1024
                         + (q & 1) * 512 + lane * 8;
        else {
            const int qq = q - ACH;
            src[p] = Wfm + (size_t)((col0 >> 4) + (qq >> 1)) * KB * 1024
                         + (qq & 1) * 512 + lane * 8;
        }
    }

    f32x4 acc[4][4];
    #pragma unroll
    for (int i = 0; i < 4; ++i)
        #pragma unroll
        for (int j = 0; j < 4; ++j) acc[i][j] = {0.f, 0.f, 0.f, 0.f};

#define STAGE(buf)                                                           \
    { _Pragma("unroll")                                                      \
      for (int p = 0; p < GPW; ++p) {                                        \
          GLL16(src[p], lds + (buf) * (NCH * 512) + (wid * GPW + p) * 512);  \
          src[p] += 1024;                                                    \
      } }

    STAGE(0)
    if (NT > 1) STAGE(1)

    for (int t = 0; t < NT; ++t) {
        if (t + 1 < NT) { asm volatile("s_waitcnt vmcnt(%0)" :: "i"(GPW) : "memory"); }
        else            { asm volatile("s_waitcnt vmcnt(0)" ::: "memory"); }
        __builtin_amdgcn_s_barrier();
        asm volatile("" ::: "memory");

        const _Float16* B0 = lds + (t & 1) * (NCH * 512);
        f16x8 ah[4], al[4], wh[4], wl[4];
        #pragma unroll
        for (int mf = 0; mf < 4; ++mf) {
            const int q = (wr * 4 + mf) * 2;
            ah[mf] = *reinterpret_cast<const f16x8*>(B0 + q * 512 + lane * 8);
            al[mf] = *reinterpret_cast<const f16x8*>(B0 + q * 512 + 512 + lane * 8);
        }
        #pragma unroll
        for (int nf = 0; nf < 4; ++nf) {
            const int q = ACH + (wc * 4 + nf) * 2;
            wh[nf] = *reinterpret_cast<const f16x8*>(B0 + q * 512 + lane * 8);
            wl[nf] = *reinterpret_cast<const f16x8*>(B0 + q * 512 + 512 + lane * 8);
        }
        __builtin_amdgcn_s_setprio(1);
        #pragma unroll
        for (int mf = 0; mf < 4; ++mf)
            #pragma unroll
            for (int nf = 0; nf < 4; ++nf) {
                acc[mf][nf] = __builtin_amdgcn_mfma_f32_16x16x32_f16(
                    ah[mf], wh[nf], acc[mf][nf], 0, 0, 0);
                acc[mf][nf] = __builtin_amdgcn_mfma_f32_16x16x32_f16(
                    ah[mf], wl[nf], acc[mf][nf], 0, 0, 0);
                acc[mf][nf] = __builtin_amdgcn_mfma_f32_16x16x32_f16(
                    al[mf], wh[nf], acc[mf][nf], 0, 0, 0);
            }
        __builtin_amdgcn_s_setprio(0);
        asm volatile("" ::: "memory");
        __builtin_amdgcn_s_barrier();
        asm volatile("" ::: "memory");
        if (t + 2 < NT) STAGE(t & 1)
    }
#undef STAGE

    // relu -> packed bounce -> fm16 out (2-way conflicts only)
    uint32_t* sb = reinterpret_cast<uint32_t*>(&lds[0]);
    #pragma unroll
    for (int ph = 0; ph < 2; ++ph) {
        if (wc == ph) {
            #pragma unroll
            for (int nf = 0; nf < 4; ++nf) {
                const int c_l = nf * 16 + (lane & 15);
                const float bv = bias0[col0 + ph * 64 + c_l];
                #pragma unroll
                for (int mf = 0; mf < 4; ++mf)
                    #pragma unroll
                    for (int j = 0; j < 4; ++j) {
                        const int r_l = wr * 64 + mf * 16 + (lane >> 4) * 4 + j;
                        const float v = fmaxf(acc[mf][nf][j] + bv, 0.f);
                        const _Float16 h = (_Float16)v;
                        const _Float16 lo = (_Float16)(v - (float)h);
                        const uint32_t pk =
                            (uint32_t)__builtin_bit_cast(uint16_t, h) |
                            ((uint32_t)__builtin_bit_cast(uint16_t, lo) << 16);
                        sb[r_l * 64 + (((c_l >> 2) ^ (r_l & 15)) << 2) + (c_l & 3)] = pk;
                    }
            }
        }
        __syncthreads();
        {
            #pragma unroll
            for (int i = 0; i < 4; ++i) {
                const int q = wid * 4 + i;
                const int T_l = q >> 1, kb_l = q & 1;
                const int r_l = T_l * 16 + (lane & 15);
                const int cb  = kb_l * 32 + (lane >> 4) * 8;
                uint32_t u[8];
                #pragma unroll
                for (int jb = 0; jb < 2; ++jb) {
                    const int chunk = ((cb >> 2) + jb) ^ (r_l & 15);
                    const uint32_t* pp = &sb[r_l * 64 + chunk * 4];
                    u[jb*4+0] = pp[0]; u[jb*4+1] = pp[1];
                    u[jb*4+2] = pp[2]; u[jb*4+3] = pp[3];
                }
                f16x8 hv, lvv;
                #pragma unroll
                for (int j = 0; j < 8; ++j) {
                    hv[j]  = __builtin_bit_cast(_Float16, (uint16_t)(u[j] & 0xffff));
                    lvv[j] = __builtin_bit_cast(_Float16, (uint16_t)(u[j] >> 16));
                }
                const size_t base =
                    ((size_t)((row0 >> 4) + T_l) * 16 +
                     ((col0 + ph * 64) >> 5) + kb_l) * 1024;
                *reinterpret_cast<f16x8*>(Cfm + base + lane * 8)       = hv;
                *reinterpret_cast<f16x8*>(Cfm + base + 512 + lane * 8) = lvv;
            }
        }
        __syncthreads();
    }
}

// ---------------------------------------------------------------------------
// heads_z (r12-proven): heads GEMM fused with reparameterization.
// ---------------------------------------------------------------------------
__global__ __launch_bounds__(256, 2)
void heads_z(const _Float16* __restrict__ Afm, const _Float16* __restrict__ Wfm,
             const float* __restrict__ mu_b, const float* __restrict__ lv_b,
             const float* __restrict__ eps,
             float* __restrict__ mu_e, float* __restrict__ lv_e,
             _Float16* __restrict__ zfm)
{
    constexpr int KB = 16, NT = 16, ACH = 8, NCH = 24, GPW = 6;
    __shared__ __align__(16) _Float16 lds[2 * NCH * 512];   // 48 KB

    const int bid = blockIdx.x;
    const int bx = (bid & 7) * 32 + (bid >> 3);
    const int lane = threadIdx.x & 63, wid = threadIdx.x >> 6;
    const int wr = wid >> 1, wc = wid & 1;
    const int row0 = bx * 64;

    const _Float16* src[GPW];
    #pragma unroll
    for (int p = 0; p < GPW; ++p) {
        const int q = wid * GPW + p;
        if (q < ACH)
            src[p] = Afm + (size_t)((row0 >> 4) + (q >> 1)) * KB * 1024
                         + (q & 1) * 512 + lane * 8;
        else {
            const int qq = q - ACH;
            src[p] = Wfm + (size_t)(qq >> 1) * KB * 1024 + (qq & 1) * 512 + lane * 8;
        }
    }

    f32x4 acc[2][4];
    #pragma unroll
    for (int i = 0; i < 2; ++i)
        #pragma unroll
        for (int j = 0; j < 4; ++j) acc[i][j] = {0.f, 0.f, 0.f, 0.f};

#define STAGE(buf)                                                           \
    { _Pragma("unroll")                                                      \
      for (int p = 0; p < GPW; ++p) {                                        \
          GLL16(src[p], lds + (buf) * (NCH * 512) + (wid * GPW + p) * 512);  \
          src[p] += 1024;                                                    \
      } }

    STAGE(0)
    STAGE(1)

    for (int t = 0; t < NT; ++t) {
        if (t + 1 < NT) { asm volatile("s_waitcnt vmcnt(%0)" :: "i"(GPW) : "memory"); }
        else            { asm volatile("s_waitcnt vmcnt(0)" ::: "memory"); }
        __builtin_amdgcn_s_barrier();
        asm volatile("" ::: "memory");

        const _Float16* B0 = lds + (t & 1) * (NCH * 512);
        f16x8 ah[2], al[2], wh[4], wl[4];
        #pragma unroll
        for (int mf = 0; mf < 2; ++mf) {
            const int q = (wr * 2 + mf) * 2;
            ah[mf] = *reinterpret_cast<const f16x8*>(B0 + q * 512 + lane * 8);
            al[mf] = *reinterpret_cast<const f16x8*>(B0 + q * 512 + 512 + lane * 8);
        }
        #pragma unroll
        for (int nf = 0; nf < 4; ++nf) {
            const int q = ACH + (wc * 4 + nf) * 2;
            wh[nf] = *reinterpret_cast<const f16x8*>(B0 + q * 512 + lane * 8);
            wl[nf] = *reinterpret_cast<const f16x8*>(B0 + q * 512 + 512 + lane * 8);
        }
        __builtin_amdgcn_s_setprio(1);
        #pragma unroll
        for (int mf = 0; mf < 2; ++mf)
            #pragma unroll
            for (int nf = 0; nf < 4; ++nf) {
                acc[mf][nf] = __builtin_amdgcn_mfma_f32_16x16x32_f16(
                    ah[mf], wh[nf], acc[mf][nf], 0, 0, 0);
                acc[mf][nf] = __builtin_amdgcn_mfma_f32_16x16x32_f16(
                    ah[mf], wl[nf], acc[mf][nf], 0, 0, 0);
                acc[mf][nf] = __builtin_amdgcn_mfma_f32_16x16x32_f16(
                    al[mf], wh[nf], acc[mf][nf], 0, 0, 0);
            }
        __builtin_amdgcn_s_setprio(0);
        asm volatile("" ::: "memory");
        __builtin_amdgcn_s_barrier();
        asm volatile("" ::: "memory");
        if (t + 2 < NT) STAGE(t & 1)
    }
#undef STAGE

    // ---- epilogue: mu|lv -> LDS, z = mu + exp(0.5 lv) * eps ----
    float* mulv = reinterpret_cast<float*>(&lds[0]);    // [64][128]
    #pragma unroll
    for (int nf = 0; nf < 4; ++nf) {
        const int c_h = wc * 64 + nf * 16 + (lane & 15);     // 0..127
        const float bv = (c_h < 64) ? mu_b[c_h] : lv_b[c_h - 64];
        #pragma unroll
        for (int mf = 0; mf < 2; ++mf)
            #pragma unroll
            for (int j = 0; j < 4; ++j) {
                const int r_l = wr * 32 + mf * 16 + (lane >> 4) * 4 + j;
                mulv[r_l * 128 + c_h] = acc[mf][nf][j] + bv;
            }
    }
    __syncthreads();
    const int tid = threadIdx.x;
    #pragma unroll
    for (int k = 0; k < 16; ++k) {
        const int id  = tid + k * 256;       // 0..4095
        const int r_l = id >> 6, c = id & 63;
        const float m = mulv[r_l * 128 + c];
        const float l = mulv[r_l * 128 + 64 + c];
        const size_t go = (size_t)(row0 + r_l) * 64 + c;
        const float ev = eps[go];
        const float z  = m + expf(0.5f * l) * ev;
        mu_e[go] = m; lv_e[go] = l;
        const _Float16 h  = (_Float16)z;
        const _Float16 lo = (_Float16)(z - (float)h);
        const size_t base = ((size_t)((row0 + r_l) >> 4) * 2 + (c >> 5)) * 1024
                            + ((r_l & 15) + ((c >> 3) & 3) * 16) * 8 + (c & 7);
        zfm[base]       = h;
        zfm[base + 512] = lo;
    }
}

// ---------------------------------------------------------------------------
// dec_out_fused v2: BM=64, BN=512 (full row/block), 512 thr = 8 waves, each
// wave owns 64 cols. A via 16 KB GLL ring-2 (1 GLL/wave/step, counted vmcnt);
// W DIRECT global->VGPR same-iteration (panel is L2-hot: 1 MB shared by all
// 256 blocks). Epilogue: per-row SSE, cross-wave reduce, running-min select,
// winner rows written straight to d_out (xhat from regs; mu/lv parallel).
// ---------------------------------------------------------------------------
__global__ __launch_bounds__(512, 1)
void dec_out_fused(const _Float16* __restrict__ Afm, const _Float16* __restrict__ Wfm,
                   const float* __restrict__ bias,
                   const float* __restrict__ Xin,
                   const float* __restrict__ mu_e, const float* __restrict__ lv_e,
                   float* __restrict__ best,
                   float* __restrict__ out_mu, float* __restrict__ out_lv,
                   float* __restrict__ out_xh, int isFirst)
{
    constexpr int KB = 16, NT = 16;
    __shared__ __align__(16) _Float16 lds[2 * 8 * 512];   // 16 KB A ring

    const int bid = blockIdx.x;
    const int bx = (bid & 7) * 32 + (bid >> 3);
    const int lane = threadIdx.x & 63, wid = threadIdx.x >> 6;
    const int row0 = bx * 64;
    const int colW = wid * 64;

    // A staging: each wave stages exactly 1 chunk (1 KB) per K-step
    const _Float16* aSrc = Afm + (size_t)((row0 >> 4) + (wid >> 1)) * KB * 1024
                               + (wid & 1) * 512 + lane * 8;
    // W: 8 direct-load pointers per wave (4 tiles x 2 planes)
    const _Float16* wSrc[8];
    #pragma unroll
    for (int i = 0; i < 8; ++i)
        wSrc[i] = Wfm + (size_t)(wid * 4 + (i >> 1)) * KB * 1024
                      + (i & 1) * 512 + lane * 8;

    f32x4 acc[4][4];
    #pragma unroll
    for (int i = 0; i < 4; ++i)
        #pragma unroll
        for (int j = 0; j < 4; ++j) acc[i][j] = {0.f, 0.f, 0.f, 0.f};

#define STAGE_A(buf)                                                         \
    { GLL16(aSrc, lds + (buf) * 4096 + wid * 512); aSrc += 1024; }

    STAGE_A(0)
    STAGE_A(1)

    for (int t = 0; t < NT; ++t) {
        // W fragments for this step (L2-hot; compiler per-use waits overlap
        // their latency with ds_read + early MFMAs)
        f16x8 wh[4], wl[4];
        #pragma unroll
        for (int nf = 0; nf < 4; ++nf) {
            wh[nf] = *reinterpret_cast<const f16x8*>(wSrc[nf * 2]);
            wl[nf] = *reinterpret_cast<const f16x8*>(wSrc[nf * 2 + 1]);
            wSrc[nf * 2]     += 1024;
            wSrc[nf * 2 + 1] += 1024;
        }
        // outstanding: [A(t)?, A(t+1), W x8] -> vmcnt(9) waits A(t) only
        if (t + 1 < NT) { asm volatile("s_waitcnt vmcnt(9)" ::: "memory"); }
        else            { asm volatile("s_waitcnt vmcnt(8)" ::: "memory"); }
        __builtin_amdgcn_s_barrier();
        asm volatile("" ::: "memory");

        const _Float16* B0 = lds + (t & 1) * 4096;
        f16x8 ah[4], al[4];
        #pragma unroll
        for (int mf = 0; mf < 4; ++mf) {
            ah[mf] = *reinterpret_cast<const f16x8*>(B0 + mf * 1024 + lane * 8);
            al[mf] = *reinterpret_cast<const f16x8*>(B0 + mf * 1024 + 512 + lane * 8);
        }
        __builtin_amdgcn_s_setprio(1);
        #pragma unroll
        for (int mf = 0; mf < 4; ++mf)
            #pragma unroll
            for (int nf = 0; nf < 4; ++nf) {
                acc[mf][nf] = __builtin_amdgcn_mfma_f32_16x16x32_f16(
                    ah[mf], wh[nf], acc[mf][nf], 0, 0, 0);
                acc[mf][nf] = __builtin_amdgcn_mfma_f32_16x16x32_f16(
                    ah[mf], wl[nf], acc[mf][nf], 0, 0, 0);
                acc[mf][nf] = __builtin_amdgcn_mfma_f32_16x16x32_f16(
                    al[mf], wh[nf], acc[mf][nf], 0, 0, 0);
            }
        __builtin_amdgcn_s_setprio(0);
        asm volatile("" ::: "memory");
        __builtin_amdgcn_s_barrier();
        asm volatile("" ::: "memory");
        if (t + 2 < NT) STAGE_A(t & 1)
    }
#undef STAGE_A

    // ---- epilogue: SSE partials, cross-wave reduce, select, winner writes --
    float* recP = reinterpret_cast<float*>(&lds[0]);      // [8][64]
    int*   winf = reinterpret_cast<int*>(recP + 8 * 64);  // [64]

    float rsum[4][4];
    #pragma unroll
    for (int mf = 0; mf < 4; ++mf)
        #pragma unroll
        for (int j = 0; j < 4; ++j) rsum[mf][j] = 0.f;
    float bv[4];
    #pragma unroll
    for (int nf = 0; nf < 4; ++nf) bv[nf] = bias[colW + nf * 16 + (lane & 15)];
    #pragma unroll
    for (int nf = 0; nf < 4; ++nf) {
        const int col = colW + nf * 16 + (lane & 15);
        #pragma unroll
        for (int mf = 0; mf < 4; ++mf)
            #pragma unroll
            for (int j = 0; j < 4; ++j) {
                const int r_l = mf * 16 + (lane >> 4) * 4 + j;
                const float v = acc[mf][nf][j] + bv[nf];
                const float d = v - Xin[(size_t)(row0 + r_l) * 512 + col];
                rsum[mf][j] += d * d;
            }
    }
    #pragma unroll
    for (int mf = 0; mf < 4; ++mf)
        #pragma unroll
        for (int j = 0; j < 4; ++j) {
            float s = rsum[mf][j];
            s += __shfl_xor(s, 1); s += __shfl_xor(s, 2);
            s += __shfl_xor(s, 4); s += __shfl_xor(s, 8);
            if ((lane & 15) == 0)
                recP[wid * 64 + mf * 16 + (lane >> 4) * 4 + j] = s;
        }
    __syncthreads();
    if (wid == 0) {
        float r = 0.f;
        #pragma unroll
        for (int w = 0; w < 8; ++w) r += recP[w * 64 + lane];
        const int grow = row0 + lane;
        const bool w = isFirst || (r < best[grow]);
        if (w) best[grow] = r;
        winf[lane] = w ? 1 : 0;
    }
    __syncthreads();
    // xhat: each wave writes its 64 cols for winning rows
    #pragma unroll
    for (int mf = 0; mf < 4; ++mf)
        #pragma unroll
        for (int j = 0; j < 4; ++j) {
            const int r_l = mf * 16 + (lane >> 4) * 4 + j;
            if (winf[r_l]) {
                #pragma unroll
                for (int nf = 0; nf < 4; ++nf) {
                    const int col = colW + nf * 16 + (lane & 15);
                    out_xh[(size_t)(row0 + r_l) * 512 + col] = acc[mf][nf][j] + bv[nf];
                }
            }
        }
    // mu/lv gather: wave wid handles rows wid*8 .. wid*8+7 (both outputs)
    #pragma unroll
    for (int k = 0; k < 8; ++k) {
        const int r = wid * 8 + k;
        if (winf[r]) {
            const size_t o = (size_t)(row0 + r) * 64 + lane;
            out_mu[o] = mu_e[o];
            out_lv[o] = lv_e[o];
        }
    }
}

extern "C" void kernel_launch(void* const* d_in, const int* in_sizes, int n_in,
                              void* d_out, int out_size, void* d_ws, size_t ws_size,
                              hipStream_t stream)
{
    const float* x         = (const float*)d_in[0];
    const float* eps       = (const float*)d_in[1];
    const float* enc_in_w  = (const float*)d_in[2];
    const float* enc_in_b  = (const float*)d_in[3];
    const float* enc_hid_w = (const float*)d_in[4];
    const float* enc_hid_b = (const float*)d_in[5];
    const float* mu_w      = (const float*)d_in[6];
    const float* mu_b      = (const float*)d_in[7];
    const float* lv_w      = (const float*)d_in[8];
    const float* lv_b      = (const float*)d_in[9];
    const float* dec_in_w  = (const float*)d_in[10];
    const float* dec_in_b  = (const float*)d_in[11];
    const float* dec_hid_w = (const float*)d_in[12];
    const float* dec_hid_b = (const float*)d_in[13];
    const float* dec_out_w = (const float*)d_in[14];
    const float* dec_out_b = (const float*)d_in[15];

    const size_t FM = (size_t)Bb * 512 * 2;
    const size_t BZ = (size_t)Bb * 64;

    _Float16* wt  = (_Float16*)d_ws;
    _Float16* xfm = wt + WT_TOTAL;
    _Float16* afm = xfm + FM;
    _Float16* bfm = afm + FM;
    _Float16* zfm = bfm + FM;
    float* fbase  = (float*)(zfm + (size_t)Bb * 64 * 2);
    float* mu_e   = fbase;
    float* lv_e   = mu_e + BZ;
    float* best   = lv_e + BZ;

    float* out_mu = (float*)d_out;
    float* out_lv = out_mu + (size_t)Bb * Zz;
    float* out_xh = out_lv + (size_t)Bb * Zz;

    const dim3 blk(256);

    fmsplit<true ><<<dim3(8, 8, 8), blk, 0, stream>>>(enc_in_w,           wt + OFF_ENCIN,  512, 512, 262144, PEREXP);
    fmsplit<true ><<<dim3(8, 8, 8), blk, 0, stream>>>(enc_hid_w,          wt + OFF_HID0,   512, 512, 524288, PEREXP);
    fmsplit<true ><<<dim3(8, 8, 8), blk, 0, stream>>>(enc_hid_w + 262144, wt + OFF_HID1,   512, 512, 524288, PEREXP);
    fmsplit<true ><<<dim3(1, 8, 8), blk, 0, stream>>>(mu_w,               wt + OFF_HEADS,  512,  64,  32768, PEREXP);
    fmsplit<true ><<<dim3(1, 8, 8), blk, 0, stream>>>(lv_w,        wt + OFF_HEADS + 65536, 512,  64,  32768, PEREXP);
    fmsplit<true ><<<dim3(8, 1, 8), blk, 0, stream>>>(dec_in_w,           wt + OFF_DECIN,   64, 512,  32768, PEREXP);
    fmsplit<true ><<<dim3(8, 8, 8), blk, 0, stream>>>(dec_hid_w,          wt + OFF_DHID0,  512, 512, 524288, PEREXP);
    fmsplit<true ><<<dim3(8, 8, 8), blk, 0, stream>>>(dec_hid_w + 262144, wt + OFF_DHID1,  512, 512, 524288, PEREXP);
    fmsplit<true ><<<dim3(8, 8, 8), blk, 0, stream>>>(dec_out_w,          wt + OFF_DECOUT, 512, 512, 262144, PEREXP);
    fmsplit<false><<<dim3(256, 8, 1), blk, 0, stream>>>(x,                xfm,             512, 512, 0, 0);

    const dim3 g512(512), g256(256), blk512(512);

    for (int e = 0; e < Eexp; ++e) {
        const _Float16* we = wt + (size_t)e * PEREXP;
        gemm_mid<512><<<g512, blk, 0, stream>>>(
            xfm, we + OFF_ENCIN, enc_in_b + (size_t)e * Hh, afm);
        gemm_mid<512><<<g512, blk, 0, stream>>>(
            afm, we + OFF_HID0, enc_hid_b + ((size_t)e * 2 + 0) * Hh, bfm);
        gemm_mid<512><<<g512, blk, 0, stream>>>(
            bfm, we + OFF_HID1, enc_hid_b + ((size_t)e * 2 + 1) * Hh, afm);
        heads_z<<<g256, blk, 0, stream>>>(
            afm, we + OFF_HEADS, mu_b + (size_t)e * Zz, lv_b + (size_t)e * Zz,
            eps, mu_e, lv_e, zfm);
        gemm_mid< 64><<<g512, blk, 0, stream>>>(
            zfm, we + OFF_DECIN, dec_in_b + (size_t)e * Hh, bfm);
        gemm_mid<512><<<g512, blk, 0, stream>>>(
            bfm, we + OFF_DHID0, dec_hid_b + ((size_t)e * 2 + 0) * Hh, afm);
        gemm_mid<512><<<g512, blk, 0, stream>>>(
            afm, we + OFF_DHID1, dec_hid_b + ((size_t)e * 2 + 1) * Hh, bfm);
        dec_out_fused<<<g256, blk512, 0, stream>>>(
            bfm, we + OFF_DECOUT, dec_out_b + (size_t)e * Dd,
            x, mu_e, lv_e, best, out_mu, out_lv, out_xh, e == 0 ? 1 : 0);
    }
}